// Round 4
// baseline (266.206 us; speedup 1.0000x reference)
//
#include <hip/hip_runtime.h>
#include <hip/hip_bf16.h>

// Pipeline: roi_align -> conv3x3(C=256->E=256 on 3x3 spatial, pad 1) -> GroupNorm(8)
//           -> ReLU -> spatial mean -> head GEMM -> +spat +sym_emb -> per-sid fuse matvec.
// Sizes: B=2, C=E=256, S=3, L=5, N=128, HMAX=128.
// 3 launches: prep(w_prep+roi) -> conv_gn_pool -> head_fuse(row-major weights, no transpose).

__device__ __forceinline__ float bf_lo(unsigned u) { return __uint_as_float(u << 16); }
__device__ __forceinline__ float bf_hi(unsigned u) { return __uint_as_float(u & 0xffff0000u); }
__device__ __forceinline__ unsigned short f2bf(float f) {
    __hip_bfloat16 h = __float2bfloat16(f);
    return *(unsigned short*)&h;
}

// ---------------- fused prep kernel ----------------
// grid.x: [0,256)    w_prep (block=c, thread=e)
//         [256,1408) roi    (block=(n,p), thread=c)
__global__ __launch_bounds__(256) void prep_k(
    const float* __restrict__ conv_w,
    const float* __restrict__ fm, const float* __restrict__ boxes,
    const int* __restrict__ batch_idx, const int* __restrict__ level_idx,
    unsigned short* __restrict__ w8, unsigned short* __restrict__ w9,
    float* __restrict__ roiT) {
    int blk = blockIdx.x;
    int t = threadIdx.x;

    if (blk < 256) {
        // conv weight repack: [e][c][9] f32 -> w8[c][e][8] + w9[c][e] bf16
        int c = blk, e = t;
        const float* src = conv_w + ((size_t)e * 256 + c) * 9;
        unsigned short tmp[8];
#pragma unroll
        for (int k = 0; k < 8; ++k) tmp[k] = f2bf(src[k]);
        ((uint4*)w8)[(size_t)c * 256 + e] = *(const uint4*)tmp;
        w9[(size_t)c * 256 + e] = f2bf(src[8]);
        return;
    }

    // ROI align: roiT[n][p][c], p = i*3 + j
    {
        int q = blk - 256;
        int n = q / 9, p = q % 9;
        int i = p / 3, j = p % 3;
        int c = t;

        int lvl = level_idx[n];
        int b = batch_idx[n];
        const float sizes[5]  = {128.f, 64.f, 32.f, 16.f, 8.f};
        const float invstr[5] = {1.f/8.f, 1.f/16.f, 1.f/32.f, 1.f/64.f, 1.f/128.f};
        float scale = invstr[lvl];
        float hv = sizes[lvl];

        float x1 = boxes[n*4+0] * scale, y1 = boxes[n*4+1] * scale;
        float x2 = boxes[n*4+2] * scale, y2 = boxes[n*4+3] * scale;
        float rw = fmaxf(x2 - x1, 1.f), rh = fmaxf(y2 - y1, 1.f);
        float x = x1 + (((float)j + 0.5f) / 3.f) * rw;
        float y = y1 + (((float)i + 0.5f) / 3.f) * rh;

        bool valid = (y > -1.f) && (y < hv) && (x > -1.f) && (x < hv);
        float yc = fminf(fmaxf(y, 0.f), hv - 1.f);
        float xc = fminf(fmaxf(x, 0.f), hv - 1.f);
        int y0 = (int)floorf(yc), x0 = (int)floorf(xc);
        int hi = (int)(hv - 1.f);
        int y1i = min(y0 + 1, hi), x1i = min(x0 + 1, hi);
        float ly = yc - (float)y0, lx = xc - (float)x0;

        const float* base = fm + (((size_t)lvl * 2 + b) * 256 + c) * (128 * 128);
        float v00 = base[y0 * 128 + x0];
        float v01 = base[y0 * 128 + x1i];
        float v10 = base[y1i * 128 + x0];
        float v11 = base[y1i * 128 + x1i];
        float v = (1.f - ly) * (1.f - lx) * v00 + (1.f - ly) * lx * v01 +
                  ly * (1.f - lx) * v10 + ly * lx * v11;
        roiT[((size_t)n * 9 + p) * 256 + c] = valid ? v : 0.f;
    }
}

// ---------------- conv3x3 + GroupNorm + ReLU + spatial-mean ----------------
// Block = (n, e-quarter): 512 blocks x 512 threads (2 blocks/CU).
// thread: e_loc = t&63, ch = t>>6 (8 c-slices of 32 channels).
// GN group = e/32: ch==0 wave lane==e_loc, groups in 32-lane halves.
__global__ __launch_bounds__(512, 2) void conv_gn_pool(
    const float* __restrict__ roiT,
    const unsigned short* __restrict__ w8, const unsigned short* __restrict__ w9,
    const float* __restrict__ gn_scale, const float* __restrict__ gn_bias,
    float* __restrict__ pooled) {
    __shared__ float lds_roi[256 * 12];   // [c][p], stride 12
    __shared__ float red[4 * 64 * 9];

    int n  = blockIdx.x >> 2;
    int eq = blockIdx.x & 3;
    int t = threadIdx.x;
    int e_loc = t & 63;
    int ch = t >> 6;
    int e = eq * 64 + e_loc;

    // stage roiT[n] (2304 f32) via float4: v4 indexes [p][c/4]
    const float4* rsrc4 = (const float4*)(roiT + (size_t)n * 2304);
    for (int v4 = t; v4 < 576; v4 += 512) {
        float4 rv = rsrc4[v4];
        int p = v4 / 64, c4 = (v4 & 63) * 4;
        lds_roi[(c4 + 0) * 12 + p] = rv.x;
        lds_roi[(c4 + 1) * 12 + p] = rv.y;
        lds_roi[(c4 + 2) * 12 + p] = rv.z;
        lds_roi[(c4 + 3) * 12 + p] = rv.w;
    }
    __syncthreads();

    float acc[9];
#pragma unroll
    for (int p = 0; p < 9; ++p) acc[p] = 0.f;

    int c0 = ch * 32;
    for (int c = c0; c < c0 + 32; ++c) {
        float r[9];
#pragma unroll
        for (int jj = 0; jj < 9; ++jj) r[jj] = lds_roi[c * 12 + jj];
        uint4 wa = ((const uint4*)w8)[(size_t)c * 256 + e];
        unsigned short w9v = w9[(size_t)c * 256 + e];
        float wv[9];
        wv[0] = bf_lo(wa.x); wv[1] = bf_hi(wa.x);
        wv[2] = bf_lo(wa.y); wv[3] = bf_hi(wa.y);
        wv[4] = bf_lo(wa.z); wv[5] = bf_hi(wa.z);
        wv[6] = bf_lo(wa.w); wv[7] = bf_hi(wa.w);
        wv[8] = bf_lo((unsigned)w9v);
#pragma unroll
        for (int ky = 0; ky < 3; ++ky) {
#pragma unroll
            for (int kx = 0; kx < 3; ++kx) {
                float w = wv[ky * 3 + kx];
#pragma unroll
                for (int oy = 0; oy < 3; ++oy) {
                    int iy = oy + ky - 1;
                    if (iy < 0 || iy > 2) continue;
#pragma unroll
                    for (int ox = 0; ox < 3; ++ox) {
                        int ix = ox + kx - 1;
                        if (ix < 0 || ix > 2) continue;
                        acc[oy * 3 + ox] = fmaf(w, r[iy * 3 + ix], acc[oy * 3 + ox]);
                    }
                }
            }
        }
    }

    // tree-reduce 8 c-slices into ch==0
    if (ch >= 4) {
#pragma unroll
        for (int p = 0; p < 9; ++p) red[((ch - 4) * 64 + e_loc) * 9 + p] = acc[p];
    }
    __syncthreads();
    if (ch < 4) {
#pragma unroll
        for (int p = 0; p < 9; ++p) acc[p] += red[(ch * 64 + e_loc) * 9 + p];
    }
    __syncthreads();
    if (ch >= 2 && ch < 4) {
#pragma unroll
        for (int p = 0; p < 9; ++p) red[((ch - 2) * 64 + e_loc) * 9 + p] = acc[p];
    }
    __syncthreads();
    if (ch < 2) {
#pragma unroll
        for (int p = 0; p < 9; ++p) acc[p] += red[(ch * 64 + e_loc) * 9 + p];
    }
    __syncthreads();
    if (ch == 1) {
#pragma unroll
        for (int p = 0; p < 9; ++p) red[e_loc * 9 + p] = acc[p];
    }
    __syncthreads();
    if (ch == 0) {
#pragma unroll
        for (int p = 0; p < 9; ++p) acc[p] += red[e_loc * 9 + p];

        float s = 0.f, sq = 0.f;
#pragma unroll
        for (int p = 0; p < 9; ++p) { s += acc[p]; sq += acc[p] * acc[p]; }
#pragma unroll
        for (int m = 16; m >= 1; m >>= 1) {
            s  += __shfl_xor(s, m, 64);
            sq += __shfl_xor(sq, m, 64);
        }
        float mean = s * (1.f / 288.f);
        float var = sq * (1.f / 288.f) - mean * mean;
        float rinv = rsqrtf(var + 1e-5f);
        float gs = gn_scale[e], gb = gn_bias[e];
        float ps = 0.f;
#pragma unroll
        for (int p = 0; p < 9; ++p) {
            float v = (acc[p] - mean) * rinv * gs + gb;
            ps += fmaxf(v, 0.f);
        }
        pooled[(size_t)n * 256 + e] = ps * (1.f / 9.f);
    }
}

// ---------------- head GEMM + spat + sym_emb + fuse matvec ----------------
// Row-major weights (no transpose): thread owns output element e, reads row W[e][:]
// contiguous via float4. k-split x2: t = kh*256 + e, each half-dot = 32 float4.
__global__ __launch_bounds__(512) void head_fuse(
    const float* __restrict__ pooled, const float* __restrict__ boxes,
    const float* __restrict__ head_w, const float* __restrict__ head_b,
    const float* __restrict__ spat_w, const float* __restrict__ spat_b,
    const float* __restrict__ sym_emb,
    const float* __restrict__ fuse_w, const float* __restrict__ fuse_b,
    const int* __restrict__ sym_ids, float* __restrict__ out) {
    __shared__ float pl[256];
    __shared__ float part[512];
    __shared__ float fin[256];
    int n = blockIdx.x;
    int t = threadIdx.x;
    int e = t & 255;
    int kh = t >> 8;                      // 0/1
    int sid = sym_ids[n];

    if (t < 256) pl[t] = pooled[(size_t)n * 256 + t];
    __syncthreads();

    {
        float acc = 0.f;
        const float4* w = (const float4*)(head_w + (size_t)e * 256 + kh * 128);
        const float4* p = (const float4*)(pl) + kh * 32;
#pragma unroll 8
        for (int k = 0; k < 32; ++k) {
            float4 wv = w[k], pv = p[k];
            acc = fmaf(pv.x, wv.x, acc);
            acc = fmaf(pv.y, wv.y, acc);
            acc = fmaf(pv.z, wv.z, acc);
            acc = fmaf(pv.w, wv.w, acc);
        }
        part[t] = acc;
    }
    __syncthreads();
    if (t < 256) {
        float ho = fmaxf(part[t] + part[t + 256] + head_b[t], 0.f);
        float4 sw = ((const float4*)spat_w)[t];
        float b0 = boxes[n*4+0], b1 = boxes[n*4+1], b2 = boxes[n*4+2], b3 = boxes[n*4+3];
        float sp = fmaxf(spat_b[t] + b0*sw.x + b1*sw.y + b2*sw.z + b3*sw.w, 0.f);
        fin[t] = ho + sp + sym_emb[sid * 256 + t];
    }
    __syncthreads();
    {
        float o = 0.f;
        const float4* w = (const float4*)(fuse_w + (size_t)sid * 65536 + (size_t)e * 256 + kh * 128);
        const float4* p = (const float4*)(fin) + kh * 32;
#pragma unroll 8
        for (int k = 0; k < 32; ++k) {
            float4 wv = w[k], pv = p[k];
            o = fmaf(pv.x, wv.x, o);
            o = fmaf(pv.y, wv.y, o);
            o = fmaf(pv.z, wv.z, o);
            o = fmaf(pv.w, wv.w, o);
        }
        part[t] = o;
    }
    __syncthreads();
    if (t < 256)
        out[(size_t)n * 256 + t] = fmaxf(part[t] + part[t + 256] + fuse_b[sid * 256 + t], 0.f);
}

extern "C" void kernel_launch(void* const* d_in, const int* in_sizes, int n_in,
                              void* d_out, int out_size, void* d_ws, size_t ws_size,
                              hipStream_t stream) {
    const float* fm      = (const float*)d_in[0];
    const float* boxes   = (const float*)d_in[1];
    const float* conv_w  = (const float*)d_in[2];
    const float* gn_s    = (const float*)d_in[3];
    const float* gn_b    = (const float*)d_in[4];
    const float* head_w  = (const float*)d_in[5];
    const float* head_b  = (const float*)d_in[6];
    const float* spat_w  = (const float*)d_in[7];
    const float* spat_b  = (const float*)d_in[8];
    const float* sym_emb = (const float*)d_in[9];
    const float* fuse_w  = (const float*)d_in[10];
    const float* fuse_b  = (const float*)d_in[11];
    const int* batch_idx = (const int*)d_in[12];
    const int* level_idx = (const int*)d_in[13];
    const int* sym_ids   = (const int*)d_in[14];
    float* outp = (float*)d_out;

    char* ws = (char*)d_ws;
    unsigned short* w8 = (unsigned short*)ws;             // [256c][256e][8] bf16: 1,048,576 B
    unsigned short* w9 = (unsigned short*)(ws + 1048576); // [256c][256e] bf16  :   131,072 B
    float* roiT    = (float*)(ws + 1179648);              // [128][9][256]      : 1,179,648 B
    float* pooled  = (float*)(ws + 2359296);              // [128][256]         :   131,072 B

    prep_k<<<1408, 256, 0, stream>>>(conv_w, fm, boxes, batch_idx, level_idx,
                                     w8, w9, roiT);
    conv_gn_pool<<<512, 512, 0, stream>>>(roiT, w8, w9, gn_s, gn_b, pooled);
    head_fuse<<<128, 512, 0, stream>>>(pooled, boxes, head_w, head_b, spat_w, spat_b,
                                       sym_emb, fuse_w, fuse_b, sym_ids, outp);
}

// Round 5
// 260.060 us; speedup vs baseline: 1.0236x; 1.0236x over previous
//
#include <hip/hip_runtime.h>
#include <hip/hip_bf16.h>

// Pipeline: roi_align -> conv3x3(C=256->E=256 on 3x3 spatial, pad 1) -> GroupNorm(8)
//           -> ReLU -> spatial mean -> head GEMM -> +spat +sym_emb -> per-sid fuse matvec.
// Sizes: B=2, C=E=256, S=3, L=5, N=128, HMAX=128.
// 3 launches: prep(w_prep + t7 transposes + roi) -> conv_gn_pool -> head_fuse.
// R4: revert to R2's transposed/coalesced head_fuse (R3's row-major was uncoalesced,
// +4us); conv processes c in pairs with float2 accs to invite v_pk_fma_f32 SLP.

__device__ __forceinline__ float bf_lo(unsigned u) { return __uint_as_float(u << 16); }
__device__ __forceinline__ float bf_hi(unsigned u) { return __uint_as_float(u & 0xffff0000u); }
__device__ __forceinline__ unsigned short f2bf(float f) {
    __hip_bfloat16 h = __float2bfloat16(f);
    return *(unsigned short*)&h;
}

// ---------------- fused prep kernel ----------------
// grid.x: [0,256)    w_prep (block=c, thread=e)
//         [256,704)  t7     (448 transpose tiles: head_w + 6x fuse_w)
//         [704,1856) roi    (block=(n,p), thread=c)
__global__ __launch_bounds__(256) void prep_k(
    const float* __restrict__ conv_w,
    const float* __restrict__ head_w, const float* __restrict__ fuse_w,
    const float* __restrict__ fm, const float* __restrict__ boxes,
    const int* __restrict__ batch_idx, const int* __restrict__ level_idx,
    unsigned short* __restrict__ w8, unsigned short* __restrict__ w9,
    float* __restrict__ head_wT, float* __restrict__ fuse_wT,
    float* __restrict__ roiT) {
    int blk = blockIdx.x;
    int t = threadIdx.x;

    if (blk < 256) {
        // conv weight repack: [e][c][9] f32 -> w8[c][e][8] + w9[c][e] bf16
        int c = blk, e = t;
        const float* src = conv_w + ((size_t)e * 256 + c) * 9;
        unsigned short tmp[8];
#pragma unroll
        for (int k = 0; k < 8; ++k) tmp[k] = f2bf(src[k]);
        ((uint4*)w8)[(size_t)c * 256 + e] = *(const uint4*)tmp;
        w9[(size_t)c * 256 + e] = f2bf(src[8]);
        return;
    }

    if (blk < 704) {
        // 32x32 tiled transpose of head_w (z=0) / fuse_w (z=1..6)
        __shared__ float tile[32][33];
        int q = blk - 256;
        int z = q >> 6;
        int rem = q & 63;
        int bx = (rem & 7) * 32, by = (rem >> 3) * 32;
        const float* in = (z == 0) ? head_w : fuse_w + (size_t)(z - 1) * 65536;
        float* out = (z == 0) ? head_wT : fuse_wT + (size_t)(z - 1) * 65536;
        int tx = t & 31, ty = t >> 5;
#pragma unroll
        for (int i = 0; i < 32; i += 8)
            tile[ty + i][tx] = in[(size_t)(by + ty + i) * 256 + bx + tx];
        __syncthreads();
#pragma unroll
        for (int i = 0; i < 32; i += 8)
            out[(size_t)(bx + ty + i) * 256 + by + tx] = tile[tx][ty + i];
        return;
    }

    // ROI align: roiT[n][p][c], p = i*3 + j
    {
        int q = blk - 704;
        int n = q / 9, p = q % 9;
        int i = p / 3, j = p % 3;
        int c = t;

        int lvl = level_idx[n];
        int b = batch_idx[n];
        const float sizes[5]  = {128.f, 64.f, 32.f, 16.f, 8.f};
        const float invstr[5] = {1.f/8.f, 1.f/16.f, 1.f/32.f, 1.f/64.f, 1.f/128.f};
        float scale = invstr[lvl];
        float hv = sizes[lvl];

        float x1 = boxes[n*4+0] * scale, y1 = boxes[n*4+1] * scale;
        float x2 = boxes[n*4+2] * scale, y2 = boxes[n*4+3] * scale;
        float rw = fmaxf(x2 - x1, 1.f), rh = fmaxf(y2 - y1, 1.f);
        float x = x1 + (((float)j + 0.5f) / 3.f) * rw;
        float y = y1 + (((float)i + 0.5f) / 3.f) * rh;

        bool valid = (y > -1.f) && (y < hv) && (x > -1.f) && (x < hv);
        float yc = fminf(fmaxf(y, 0.f), hv - 1.f);
        float xc = fminf(fmaxf(x, 0.f), hv - 1.f);
        int y0 = (int)floorf(yc), x0 = (int)floorf(xc);
        int hi = (int)(hv - 1.f);
        int y1i = min(y0 + 1, hi), x1i = min(x0 + 1, hi);
        float ly = yc - (float)y0, lx = xc - (float)x0;

        const float* base = fm + (((size_t)lvl * 2 + b) * 256 + c) * (128 * 128);
        float v00 = base[y0 * 128 + x0];
        float v01 = base[y0 * 128 + x1i];
        float v10 = base[y1i * 128 + x0];
        float v11 = base[y1i * 128 + x1i];
        float v = (1.f - ly) * (1.f - lx) * v00 + (1.f - ly) * lx * v01 +
                  ly * (1.f - lx) * v10 + ly * lx * v11;
        roiT[((size_t)n * 9 + p) * 256 + c] = valid ? v : 0.f;
    }
}

// ---------------- conv3x3 + GroupNorm + ReLU + spatial-mean ----------------
// Block = (n, e-quarter): 512 blocks x 512 threads (2 blocks/CU).
// thread: e_loc = t&63, ch = t>>6 (8 c-slices of 32 channels, processed in pairs).
// GN group = e/32: ch==0 wave lane==e_loc, groups in 32-lane halves.
__global__ __launch_bounds__(512, 2) void conv_gn_pool(
    const float* __restrict__ roiT,
    const unsigned short* __restrict__ w8, const unsigned short* __restrict__ w9,
    const float* __restrict__ gn_scale, const float* __restrict__ gn_bias,
    float* __restrict__ pooled) {
    __shared__ float lds_roi[256 * 12];   // [c][p], stride 12
    __shared__ float red[4 * 64 * 9];

    int n  = blockIdx.x >> 2;
    int eq = blockIdx.x & 3;
    int t = threadIdx.x;
    int e_loc = t & 63;
    int ch = t >> 6;
    int e = eq * 64 + e_loc;

    // stage roiT[n] (2304 f32) via float4
    const float4* rsrc4 = (const float4*)(roiT + (size_t)n * 2304);
    for (int v4 = t; v4 < 576; v4 += 512) {
        float4 rv = rsrc4[v4];
        int p = v4 / 64, c4 = (v4 & 63) * 4;
        lds_roi[(c4 + 0) * 12 + p] = rv.x;
        lds_roi[(c4 + 1) * 12 + p] = rv.y;
        lds_roi[(c4 + 2) * 12 + p] = rv.z;
        lds_roi[(c4 + 3) * 12 + p] = rv.w;
    }
    __syncthreads();

    float accx[9], accy[9];   // channel-pair accumulators (invite v_pk_fma_f32)
#pragma unroll
    for (int p = 0; p < 9; ++p) { accx[p] = 0.f; accy[p] = 0.f; }

    int c0 = ch * 32;
    for (int c = c0; c < c0 + 32; c += 2) {
        float ra[9], rb[9];
#pragma unroll
        for (int jj = 0; jj < 9; ++jj) {
            ra[jj] = lds_roi[c * 12 + jj];
            rb[jj] = lds_roi[(c + 1) * 12 + jj];
        }
        uint4 wa4 = ((const uint4*)w8)[(size_t)c * 256 + e];
        uint4 wb4 = ((const uint4*)w8)[(size_t)(c + 1) * 256 + e];
        float wa[9], wb[9];
        wa[0] = bf_lo(wa4.x); wa[1] = bf_hi(wa4.x);
        wa[2] = bf_lo(wa4.y); wa[3] = bf_hi(wa4.y);
        wa[4] = bf_lo(wa4.z); wa[5] = bf_hi(wa4.z);
        wa[6] = bf_lo(wa4.w); wa[7] = bf_hi(wa4.w);
        wa[8] = bf_lo((unsigned)w9[(size_t)c * 256 + e]);
        wb[0] = bf_lo(wb4.x); wb[1] = bf_hi(wb4.x);
        wb[2] = bf_lo(wb4.y); wb[3] = bf_hi(wb4.y);
        wb[4] = bf_lo(wb4.z); wb[5] = bf_hi(wb4.z);
        wb[6] = bf_lo(wb4.w); wb[7] = bf_hi(wb4.w);
        wb[8] = bf_lo((unsigned)w9[(size_t)(c + 1) * 256 + e]);
#pragma unroll
        for (int ky = 0; ky < 3; ++ky) {
#pragma unroll
            for (int kx = 0; kx < 3; ++kx) {
                float wav = wa[ky * 3 + kx], wbv = wb[ky * 3 + kx];
#pragma unroll
                for (int oy = 0; oy < 3; ++oy) {
                    int iy = oy + ky - 1;
                    if (iy < 0 || iy > 2) continue;
#pragma unroll
                    for (int ox = 0; ox < 3; ++ox) {
                        int ix = ox + kx - 1;
                        if (ix < 0 || ix > 2) continue;
                        int o = oy * 3 + ox, in = iy * 3 + ix;
                        accx[o] = fmaf(wav, ra[in], accx[o]);
                        accy[o] = fmaf(wbv, rb[in], accy[o]);
                    }
                }
            }
        }
    }

    float acc[9];
#pragma unroll
    for (int p = 0; p < 9; ++p) acc[p] = accx[p] + accy[p];

    // tree-reduce 8 c-slices into ch==0
    if (ch >= 4) {
#pragma unroll
        for (int p = 0; p < 9; ++p) red[((ch - 4) * 64 + e_loc) * 9 + p] = acc[p];
    }
    __syncthreads();
    if (ch < 4) {
#pragma unroll
        for (int p = 0; p < 9; ++p) acc[p] += red[(ch * 64 + e_loc) * 9 + p];
    }
    __syncthreads();
    if (ch >= 2 && ch < 4) {
#pragma unroll
        for (int p = 0; p < 9; ++p) red[((ch - 2) * 64 + e_loc) * 9 + p] = acc[p];
    }
    __syncthreads();
    if (ch < 2) {
#pragma unroll
        for (int p = 0; p < 9; ++p) acc[p] += red[(ch * 64 + e_loc) * 9 + p];
    }
    __syncthreads();
    if (ch == 1) {
#pragma unroll
        for (int p = 0; p < 9; ++p) red[e_loc * 9 + p] = acc[p];
    }
    __syncthreads();
    if (ch == 0) {
#pragma unroll
        for (int p = 0; p < 9; ++p) acc[p] += red[e_loc * 9 + p];

        float s = 0.f, sq = 0.f;
#pragma unroll
        for (int p = 0; p < 9; ++p) { s += acc[p]; sq += acc[p] * acc[p]; }
#pragma unroll
        for (int m = 16; m >= 1; m >>= 1) {
            s  += __shfl_xor(s, m, 64);
            sq += __shfl_xor(sq, m, 64);
        }
        float mean = s * (1.f / 288.f);
        float var = sq * (1.f / 288.f) - mean * mean;
        float rinv = rsqrtf(var + 1e-5f);
        float gs = gn_scale[e], gb = gn_bias[e];
        float ps = 0.f;
#pragma unroll
        for (int p = 0; p < 9; ++p) {
            float v = (acc[p] - mean) * rinv * gs + gb;
            ps += fmaxf(v, 0.f);
        }
        pooled[(size_t)n * 256 + e] = ps * (1.f / 9.f);
    }
}

// ---------------- head GEMM + spat + sym_emb + fuse matvec (k-split x2) ----------------
// block = n (128 blocks x 512 threads). t = kh*256 + e; transposed weights so
// lane-consecutive threads read consecutive addresses (coalesced).
__global__ __launch_bounds__(512) void head_fuse(
    const float* __restrict__ pooled, const float* __restrict__ boxes,
    const float* __restrict__ head_wT, const float* __restrict__ head_b,
    const float* __restrict__ spat_w, const float* __restrict__ spat_b,
    const float* __restrict__ sym_emb,
    const float* __restrict__ fuse_wT, const float* __restrict__ fuse_b,
    const int* __restrict__ sym_ids, float* __restrict__ out) {
    __shared__ float pl[256];
    __shared__ float part[512];
    __shared__ float fin[256];
    int n = blockIdx.x;
    int t = threadIdx.x;
    int e = t & 255;
    int kh = t >> 8;                      // 0/1
    int sid = sym_ids[n];

    if (t < 256) pl[t] = pooled[(size_t)n * 256 + t];
    __syncthreads();

    {
        float acc = 0.f;
        const float* w = head_wT + (size_t)(kh * 128) * 256 + e;
        const float* p = pl + kh * 128;
#pragma unroll 8
        for (int k = 0; k < 128; ++k) acc = fmaf(p[k], w[k * 256], acc);
        part[t] = acc;
    }
    __syncthreads();
    if (t < 256) {
        float ho = fmaxf(part[t] + part[t + 256] + head_b[t], 0.f);
        float4 sw = ((const float4*)spat_w)[t];
        float b0 = boxes[n*4+0], b1 = boxes[n*4+1], b2 = boxes[n*4+2], b3 = boxes[n*4+3];
        float sp = fmaxf(spat_b[t] + b0*sw.x + b1*sw.y + b2*sw.z + b3*sw.w, 0.f);
        fin[t] = ho + sp + sym_emb[sid * 256 + t];
    }
    __syncthreads();
    {
        float o = 0.f;
        const float* w = fuse_wT + (size_t)sid * 65536 + (size_t)(kh * 128) * 256 + e;
        const float* p = fin + kh * 128;
#pragma unroll 8
        for (int k = 0; k < 128; ++k) o = fmaf(p[k], w[k * 256], o);
        part[t] = o;
    }
    __syncthreads();
    if (t < 256)
        out[(size_t)n * 256 + t] = fmaxf(part[t] + part[t + 256] + fuse_b[sid * 256 + t], 0.f);
}

extern "C" void kernel_launch(void* const* d_in, const int* in_sizes, int n_in,
                              void* d_out, int out_size, void* d_ws, size_t ws_size,
                              hipStream_t stream) {
    const float* fm      = (const float*)d_in[0];
    const float* boxes   = (const float*)d_in[1];
    const float* conv_w  = (const float*)d_in[2];
    const float* gn_s    = (const float*)d_in[3];
    const float* gn_b    = (const float*)d_in[4];
    const float* head_w  = (const float*)d_in[5];
    const float* head_b  = (const float*)d_in[6];
    const float* spat_w  = (const float*)d_in[7];
    const float* spat_b  = (const float*)d_in[8];
    const float* sym_emb = (const float*)d_in[9];
    const float* fuse_w  = (const float*)d_in[10];
    const float* fuse_b  = (const float*)d_in[11];
    const int* batch_idx = (const int*)d_in[12];
    const int* level_idx = (const int*)d_in[13];
    const int* sym_ids   = (const int*)d_in[14];
    float* outp = (float*)d_out;

    char* ws = (char*)d_ws;
    unsigned short* w8 = (unsigned short*)ws;             // [256c][256e][8] bf16: 1,048,576 B
    unsigned short* w9 = (unsigned short*)(ws + 1048576); // [256c][256e] bf16  :   131,072 B
    float* head_wT = (float*)(ws + 1179648);              // [256][256]         :   262,144 B
    float* fuse_wT = (float*)(ws + 1441792);              // [6][256][256]      : 1,572,864 B
    float* roiT    = (float*)(ws + 3014656);              // [128][9][256]      : 1,179,648 B
    float* pooled  = (float*)(ws + 4194304);              // [128][256]         :   131,072 B

    prep_k<<<1856, 256, 0, stream>>>(conv_w, head_w, fuse_w, fm, boxes,
                                     batch_idx, level_idx,
                                     w8, w9, head_wT, fuse_wT, roiT);
    conv_gn_pool<<<512, 512, 0, stream>>>(roiT, w8, w9, gn_s, gn_b, pooled);
    head_fuse<<<128, 512, 0, stream>>>(pooled, boxes, head_wT, head_b, spat_w, spat_b,
                                       sym_emb, fuse_wT, fuse_b, sym_ids, outp);
}